// Round 20
// baseline (90.457 us; speedup 1.0000x reference)
//
#include <hip/hip_runtime.h>

// GATConv fused pipeline, MI355X.
// R20: k_aggr REVERTED to R17 form (4 dsts/wave, 16 lanes/dst, 32-edge
//   chunks, inline alpha) — measured local optimum: R18 (precompute split,
//   91.1us) and R19 (8 dsts/wave, occ 52%, 90.0us) both regressed vs R17's
//   86.6us. Added: straight-line fast path for deg<=32 (~97% of dsts).
// k_fused (scatter-first block-split) and k_fsort unchanged from R17.
// word = dst_low:8 | src:17 (n<=131072). rowptrB[b*257+dl] = abs seg starts.

#define NEG_SLOPE 0.2f
#define NBC_MAX 512
#define SCAP 6144

typedef __attribute__((ext_vector_type(8))) short bf16x8;
typedef __attribute__((ext_vector_type(4))) float f32x4;

__device__ __forceinline__ float leaky(float v) {
    return v > 0.f ? v : NEG_SLOPE * v;
}
__device__ __forceinline__ unsigned short f2bf(float f) {
    unsigned b = __float_as_uint(f);
    return (unsigned short)((b + 0x7FFFu + ((b >> 16) & 1u)) >> 16);
}
__device__ __forceinline__ float bf2f(unsigned short u) {
    return __uint_as_float(((unsigned)u) << 16);
}
// fma 8 bf16 features (packed in int4) into acc[8] with weight w
__device__ __forceinline__ void bf8_fma(float* acc, int4 u, float w) {
    acc[0] = fmaf(__uint_as_float((unsigned)u.x << 16), w, acc[0]);
    acc[1] = fmaf(__uint_as_float((unsigned)u.x & 0xFFFF0000u), w, acc[1]);
    acc[2] = fmaf(__uint_as_float((unsigned)u.y << 16), w, acc[2]);
    acc[3] = fmaf(__uint_as_float((unsigned)u.y & 0xFFFF0000u), w, acc[3]);
    acc[4] = fmaf(__uint_as_float((unsigned)u.z << 16), w, acc[4]);
    acc[5] = fmaf(__uint_as_float((unsigned)u.z & 0xFFFF0000u), w, acc[5]);
    acc[6] = fmaf(__uint_as_float((unsigned)u.w << 16), w, acc[6]);
    acc[7] = fmaf(__uint_as_float((unsigned)u.w & 0xFFFF0000u), w, acc[7]);
}

// exclusive scan of sd[0..len) in place; sd must have len+1 slots.
__device__ __forceinline__ void lds_excl_scan(int* sd, int len) {
    __syncthreads();
    if (threadIdx.x < 64) {
        int lane = threadIdx.x;
        int carry = 0;
        for (int c0 = 0; c0 < len; c0 += 64) {
            int idx = c0 + lane;
            int v = (idx < len) ? sd[idx] : 0;
            int s = v;
            for (int off = 1; off < 64; off <<= 1) {
                int t = __shfl_up(s, off);
                if (lane >= off) s += t;
            }
            if (idx < len) sd[idx] = carry + s - v;
            carry += __shfl(s, 63);
        }
        if (lane == 0) sd[len] = carry;
    }
    __syncthreads();
}

// ------------------------------------------------- fused cscatter | gemm
__global__ __launch_bounds__(256) void k_fused(
    const float* __restrict__ x, const float* __restrict__ Wg,
    const float* __restrict__ att_s, const float* __restrict__ att_d,
    unsigned short* __restrict__ h2, float* __restrict__ a_src,
    float* __restrict__ a_dst,
    const int* __restrict__ srcv, const int* __restrict__ dstv,
    int* __restrict__ gcursor, int* __restrict__ words,
    int n, int e, int nbc, int neb) {
    __shared__ char sbuf[16384 + 8192 + (NBC_MAX * 3 + 1) * 4];  // 30.7 KB

    if ((int)blockIdx.x >= neb) {
        // ---------------- gemm path ----------------
        unsigned short* Wh = (unsigned short*)sbuf;  // [col][136]
        {
            const float4* wg4 = (const float4*)Wg;  // [k=128][col=64]
#pragma unroll
            for (int i = 0; i < 8; ++i) {
                int f = threadIdx.x + i * 256;
                float4 w = wg4[f];
                int k = f >> 4;
                int c0 = (f & 15) << 2;
                Wh[(c0 + 0) * 136 + k] = f2bf(w.x);
                Wh[(c0 + 1) * 136 + k] = f2bf(w.y);
                Wh[(c0 + 2) * 136 + k] = f2bf(w.z);
                Wh[(c0 + 3) * 136 + k] = f2bf(w.w);
            }
        }
        __syncthreads();

        const int lane = threadIdx.x & 63;
        const int wave = threadIdx.x >> 6;
        const int rb = ((int)blockIdx.x - neb) * 64 + wave * 16;
        const int arow = rb + (lane & 15);
        const int kb = (lane >> 4) << 3;
        const int col = lane & 15;

        f32x4 acc[4];
#pragma unroll
        for (int ct = 0; ct < 4; ++ct) acc[ct] = (f32x4){0.f, 0.f, 0.f, 0.f};

#pragma unroll
        for (int ks = 0; ks < 4; ++ks) {
            const int k0 = ks * 32 + kb;
            float av[8];
            if (arow < n) {
                float4 a0 = *(const float4*)(x + (size_t)arow * 128 + k0);
                float4 a1 = *(const float4*)(x + (size_t)arow * 128 + k0 + 4);
                av[0] = a0.x; av[1] = a0.y; av[2] = a0.z; av[3] = a0.w;
                av[4] = a1.x; av[5] = a1.y; av[6] = a1.z; av[7] = a1.w;
            } else {
#pragma unroll
                for (int j = 0; j < 8; ++j) av[j] = 0.f;
            }
            bf16x8 ah;
#pragma unroll
            for (int j = 0; j < 8; ++j) ah[j] = (short)f2bf(av[j]);
#pragma unroll
            for (int ct = 0; ct < 4; ++ct) {
                const bf16x8 bh = *(const bf16x8*)(&Wh[(ct * 16 + col) * 136 + k0]);
                acc[ct] = __builtin_amdgcn_mfma_f32_16x16x32_bf16(ah, bh, acc[ct], 0, 0, 0);
            }
        }

        float as_f[4], ad_f[4];
#pragma unroll
        for (int ct = 0; ct < 4; ++ct) {
            as_f[ct] = att_s[ct * 16 + col];
            ad_f[ct] = att_d[ct * 16 + col];
        }
#pragma unroll
        for (int reg = 0; reg < 4; ++reg) {
            const int row = rb + ((lane >> 4) << 2) + reg;
            float s = 0.f, t = 0.f;
#pragma unroll
            for (int ct = 0; ct < 4; ++ct) {
                float v = acc[ct][reg];
                s = fmaf(v, as_f[ct], s);
                t = fmaf(v, ad_f[ct], t);
                if (row < n) h2[(size_t)row * 64 + ct * 16 + col] = f2bf(v);
            }
#pragma unroll
            for (int o = 1; o < 16; o <<= 1) {
                s += __shfl_xor(s, o);
                t += __shfl_xor(t, o);
            }
            if (col == 0 && row < n) { a_src[row] = s; a_dst[row] = t; }
        }
    } else {
        // ---------------- cscatter path ----------------
        int* wordA = (int*)sbuf;                            // [4096]
        unsigned short* buckA = (unsigned short*)(sbuf + 16384);  // [4096]
        int* meta  = (int*)(sbuf + 24576);
        int* sc    = meta;                 // [NBC_MAX+1]
        int* offs  = meta + NBC_MAX + 1;   // [NBC_MAX]
        int* gbase = meta + 2 * NBC_MAX + 1;
        const int tid = threadIdx.x;
        for (int t = tid; t < nbc; t += 256) { sc[t] = 0; offs[t] = 0; }
        __syncthreads();
        const int base = (int)blockIdx.x * 4096;
        int s_[16], d_[16];
#pragma unroll
        for (int k = 0; k < 4; ++k) {
            const int i0 = base + (k * 256 + tid) * 4;
            if (i0 + 4 <= e) {
                int4 s4 = *(const int4*)(srcv + i0);
                int4 d4 = *(const int4*)(dstv + i0);
                s_[k * 4 + 0] = s4.x; d_[k * 4 + 0] = d4.x;
                s_[k * 4 + 1] = s4.y; d_[k * 4 + 1] = d4.y;
                s_[k * 4 + 2] = s4.z; d_[k * 4 + 2] = d4.z;
                s_[k * 4 + 3] = s4.w; d_[k * 4 + 3] = d4.w;
            } else {
#pragma unroll
                for (int j = 0; j < 4; ++j) {
                    int i = i0 + j;
                    if (i < e) { s_[k * 4 + j] = srcv[i]; d_[k * 4 + j] = dstv[i]; }
                    else d_[k * 4 + j] = -1;
                }
            }
        }
#pragma unroll
        for (int k = 0; k < 16; ++k)
            if (d_[k] >= 0) atomicAdd(&sc[d_[k] >> 8], 1);
        lds_excl_scan(sc, nbc);
        for (int t = tid; t < nbc; t += 256) {
            int c = sc[t + 1] - sc[t];
            if (c) gbase[t] = t * SCAP + atomicAdd(&gcursor[t], c);
        }
        __syncthreads();
#pragma unroll
        for (int k = 0; k < 16; ++k) {
            if (d_[k] >= 0) {
                int bb = d_[k] >> 8;
                int r = atomicAdd(&offs[bb], 1);
                int idx = sc[bb] + r;
                wordA[idx] = ((d_[k] & 255) << 17) | s_[k];
                buckA[idx] = (unsigned short)bb;
            }
        }
        __syncthreads();
        const int tot = sc[nbc];
        for (int p = tid; p < tot; p += 256) {
            int bb = buckA[p];
            int gi = gbase[bb] + (p - sc[bb]);
            if (gi < (bb + 1) * SCAP) {  // overflow clamp (never hot)
                words[gi] = wordA[p];
            }
        }
    }
}

// ------------------------------------------------- fine sort (pure, 1-read)
__global__ __launch_bounds__(256) void k_fsort(
    const int* __restrict__ words, const int* __restrict__ gcursor,
    int* __restrict__ words2, int* __restrict__ rowptrB, int n) {
    __shared__ int rp[257];
    __shared__ int offs[256];
    __shared__ int staged[SCAP];    // 24 KB
    __shared__ int sorted_[SCAP];   // 24 KB
    const int b = blockIdx.x;
    const int base = b * SCAP;
    const int cnt = min(gcursor[b], SCAP);
    const int tid = threadIdx.x;
    rp[tid] = 0;
    offs[tid] = 0;
    if (tid == 0) rp[256] = 0;
    __syncthreads();
    for (int p = tid; p < cnt; p += 256) {
        int w = words[base + p];
        staged[p] = w;
        atomicAdd(&rp[(w >> 17) & 255], 1);
    }
    lds_excl_scan(rp, 256);
    for (int p = tid; p < cnt; p += 256) {
        int w = staged[p];
        int dl = (w >> 17) & 255;
        int r = atomicAdd(&offs[dl], 1);
        sorted_[rp[dl] + r] = w;
    }
    __syncthreads();
    const int cnt4 = cnt >> 2;
    for (int q = tid; q < cnt4; q += 256)
        ((int4*)(words2 + base))[q] = ((const int4*)sorted_)[q];
    for (int p = (cnt4 << 2) + tid; p < cnt; p += 256)
        words2[base + p] = sorted_[p];
    for (int t = tid; t <= 256; t += 256)
        rowptrB[b * 257 + t] = base + rp[t];
}

// ------------------------------------------------- weighted gather-aggregate
// 4 dsts/wave (16 lanes/dst: 2 row-pairs x 8 feat-octets); 32-edge chunks
// (2 guarded words2 loads + inline alpha per lane). Fast path for deg<=32.
__global__ __launch_bounds__(256) void k_aggr(
    const unsigned short* __restrict__ h2, const float* __restrict__ a_src,
    const float* __restrict__ a_dst, const int* __restrict__ rowptrB,
    const int* __restrict__ words2, float* __restrict__ out, int n) {
    const int lane = threadIdx.x & 63;
    const int wave = threadIdx.x >> 6;
    const int d = blockIdx.x * 16 + wave * 4 + (lane >> 4);
    if (d >= n) return;
    const int b = d >> 8;
    const int dl = d & 255;
    const int s0 = rowptrB[b * 257 + dl];
    const int deg = rowptrB[b * 257 + dl + 1] - s0;
    const float adstd = a_dst[d];
    const float wself = __expf(leaky(a_src[d] + adstd));

    const int r = (lane >> 3) & 1;    // row pair 0/1
    const int f0 = (lane & 7) << 3;   // feature octet
    const int gb = lane & 48;         // group base lane
    const int lane15 = lane & 15;
    float acc[8] = {0.f, 0.f, 0.f, 0.f, 0.f, 0.f, 0.f, 0.f};
    float wsum_l = 0.f;
    if (r == 0) {  // self loop
        int4 u = *(const int4*)(h2 + (size_t)d * 64 + f0);
        bf8_fma(acc, u, wself);
    }
    if (deg <= 32) {
        // ---- fast path: single chunk, straight-line ----
        const int jA = lane15;
        const int jB = jA + 16;
        int srcA = 0, srcB = 0;
        float wA = 0.f, wB = 0.f;
        if (jA < deg) srcA = words2[s0 + jA] & 0x1FFFF;
        if (jB < deg) srcB = words2[s0 + jB] & 0x1FFFF;
        if (jA < deg) wA = __expf(leaky(a_src[srcA] + adstd));
        if (jB < deg) wB = __expf(leaky(a_src[srcB] + adstd));
        wsum_l = wA + wB;
#pragma unroll
        for (int c0 = 0; c0 < 16; c0 += 2) {
            const int sl = gb | (c0 + r);
            int sjA = __shfl(srcA, sl);
            float wjA = __shfl(wA, sl);
            int sjB = __shfl(srcB, sl);
            float wjB = __shfl(wB, sl);
            if (c0 + r < deg) {
                int4 u = *(const int4*)(h2 + (size_t)sjA * 64 + f0);
                bf8_fma(acc, u, wjA);
            }
            if (16 + c0 + r < deg) {
                int4 u = *(const int4*)(h2 + (size_t)sjB * 64 + f0);
                bf8_fma(acc, u, wjB);
            }
        }
    } else {
        for (int cb = 0; cb < deg; cb += 32) {
            const int jA = cb + lane15;
            const int jB = jA + 16;
            int srcA = 0, srcB = 0;
            float wA = 0.f, wB = 0.f;
            if (jA < deg) srcA = words2[s0 + jA] & 0x1FFFF;
            if (jB < deg) srcB = words2[s0 + jB] & 0x1FFFF;
            if (jA < deg) wA = __expf(leaky(a_src[srcA] + adstd));
            if (jB < deg) wB = __expf(leaky(a_src[srcB] + adstd));
            wsum_l += wA + wB;
            const int cnt = min(32, deg - cb);
#pragma unroll
            for (int c0 = 0; c0 < 16; c0 += 2) {
                const int sl = gb | (c0 + r);
                int sjA = __shfl(srcA, sl);
                float wjA = __shfl(wA, sl);
                int sjB = __shfl(srcB, sl);
                float wjB = __shfl(wB, sl);
                if (c0 + r < cnt) {
                    int4 u = *(const int4*)(h2 + (size_t)sjA * 64 + f0);
                    bf8_fma(acc, u, wjA);
                }
                if (16 + c0 + r < cnt) {
                    int4 u = *(const int4*)(h2 + (size_t)sjB * 64 + f0);
                    bf8_fma(acc, u, wjB);
                }
            }
        }
    }
    // wsum over the 16-lane group
#pragma unroll
    for (int o = 8; o >= 1; o >>= 1) wsum_l += __shfl_xor(wsum_l, o);
    const float inv = 1.0f / (wsum_l + wself + 1e-16f);
    // combine row pairs
#pragma unroll
    for (int i = 0; i < 8; ++i) acc[i] += __shfl_xor(acc[i], 8);
    if (r == 0) {
        float* op = out + (size_t)d * 64 + f0;
        *(float4*)op = make_float4(acc[0] * inv, acc[1] * inv,
                                   acc[2] * inv, acc[3] * inv);
        *(float4*)(op + 4) = make_float4(acc[4] * inv, acc[5] * inv,
                                         acc[6] * inv, acc[7] * inv);
    }
}

extern "C" void kernel_launch(void* const* d_in, const int* in_sizes, int n_in,
                              void* d_out, int out_size, void* d_ws, size_t ws_size,
                              hipStream_t stream) {
    const float* x = (const float*)d_in[0];
    const float* W = (const float*)d_in[1];
    const float* att_s = (const float*)d_in[2];
    const float* att_d = (const float*)d_in[3];
    const int* ei = (const int*)d_in[4];
    const int n = in_sizes[0] / 128;
    const int e = in_sizes[4] / 2;
    const int* srcv = ei;
    const int* dstv = ei + e;
    float* out = (float*)d_out;

    char* ws = (char*)d_ws;
    size_t off = 0;
    auto carve = [&](size_t bytes) -> void* {
        void* p = ws + off;
        off = (off + bytes + 63) & ~(size_t)63;
        return p;
    };
    const int nbc = (n + 255) >> 8;  // coarse buckets (<= NBC_MAX)
    unsigned short* h2 = (unsigned short*)carve((size_t)n * 64 * 2);
    float* a_src  = (float*)carve((size_t)n * 4);
    float* a_dst  = (float*)carve((size_t)n * 4);
    int* gcursor  = (int*)carve((size_t)NBC_MAX * 4);
    int* rowptrB  = (int*)carve((size_t)nbc * 257 * 4);
    int* words    = (int*)carve((size_t)nbc * SCAP * 4);
    int* words2   = (int*)carve((size_t)nbc * SCAP * 4);
    (void)ws_size; (void)n_in; (void)out_size;

    const int neb = (e + 4095) / 4096;
    const int gB = (n + 63) / 64;

    hipMemsetAsync(gcursor, 0, (size_t)NBC_MAX * 4, stream);
    k_fused<<<neb + gB, 256, 0, stream>>>(x, W, att_s, att_d, h2, a_src, a_dst,
                                          srcv, dstv, gcursor, words, n, e, nbc, neb);
    k_fsort<<<nbc, 256, 0, stream>>>(words, gcursor, words2, rowptrB, n);
    k_aggr<<<(n + 15) / 16, 256, 0, stream>>>(h2, a_src, a_dst, rowptrB, words2, out, n);
}

// Round 21
// 87.908 us; speedup vs baseline: 1.0290x; 1.0290x over previous
//
#include <hip/hip_runtime.h>

// GATConv fused pipeline, MI355X.
// R21: exact revert to R17 (measured best: 86.6us). R18 (softmax
//   precompute-in-fsort, 91.1), R19 (8 dst/wave, 90.0), R20 (deg<=32 fast
//   path, 90.5) all regressed — k_aggr is latency-bound; occupancy >
//   instruction count. R17 form: 4 dsts/wave, 16 lanes/dst, 32-edge chunks,
//   inline alpha, single uniform loop.
// Pipeline: memset(gcursor 2KB) -> k_fused(scatter blocks [0,neb) | gemm
//   blocks after; 30.7KB LDS union) -> k_fsort (pure 1-read counting sort,
//   int4 writes) -> k_aggr.
// word = dst_low:8 | src:17 (n<=131072). rowptrB[b*257+dl] = abs seg starts.

#define NEG_SLOPE 0.2f
#define NBC_MAX 512
#define SCAP 6144

typedef __attribute__((ext_vector_type(8))) short bf16x8;
typedef __attribute__((ext_vector_type(4))) float f32x4;

__device__ __forceinline__ float leaky(float v) {
    return v > 0.f ? v : NEG_SLOPE * v;
}
__device__ __forceinline__ unsigned short f2bf(float f) {
    unsigned b = __float_as_uint(f);
    return (unsigned short)((b + 0x7FFFu + ((b >> 16) & 1u)) >> 16);
}
__device__ __forceinline__ float bf2f(unsigned short u) {
    return __uint_as_float(((unsigned)u) << 16);
}
// fma 8 bf16 features (packed in int4) into acc[8] with weight w
__device__ __forceinline__ void bf8_fma(float* acc, int4 u, float w) {
    acc[0] = fmaf(__uint_as_float((unsigned)u.x << 16), w, acc[0]);
    acc[1] = fmaf(__uint_as_float((unsigned)u.x & 0xFFFF0000u), w, acc[1]);
    acc[2] = fmaf(__uint_as_float((unsigned)u.y << 16), w, acc[2]);
    acc[3] = fmaf(__uint_as_float((unsigned)u.y & 0xFFFF0000u), w, acc[3]);
    acc[4] = fmaf(__uint_as_float((unsigned)u.z << 16), w, acc[4]);
    acc[5] = fmaf(__uint_as_float((unsigned)u.z & 0xFFFF0000u), w, acc[5]);
    acc[6] = fmaf(__uint_as_float((unsigned)u.w << 16), w, acc[6]);
    acc[7] = fmaf(__uint_as_float((unsigned)u.w & 0xFFFF0000u), w, acc[7]);
}

// exclusive scan of sd[0..len) in place; sd must have len+1 slots.
__device__ __forceinline__ void lds_excl_scan(int* sd, int len) {
    __syncthreads();
    if (threadIdx.x < 64) {
        int lane = threadIdx.x;
        int carry = 0;
        for (int c0 = 0; c0 < len; c0 += 64) {
            int idx = c0 + lane;
            int v = (idx < len) ? sd[idx] : 0;
            int s = v;
            for (int off = 1; off < 64; off <<= 1) {
                int t = __shfl_up(s, off);
                if (lane >= off) s += t;
            }
            if (idx < len) sd[idx] = carry + s - v;
            carry += __shfl(s, 63);
        }
        if (lane == 0) sd[len] = carry;
    }
    __syncthreads();
}

// ------------------------------------------------- fused cscatter | gemm
__global__ __launch_bounds__(256) void k_fused(
    const float* __restrict__ x, const float* __restrict__ Wg,
    const float* __restrict__ att_s, const float* __restrict__ att_d,
    unsigned short* __restrict__ h2, float* __restrict__ a_src,
    float* __restrict__ a_dst,
    const int* __restrict__ srcv, const int* __restrict__ dstv,
    int* __restrict__ gcursor, int* __restrict__ words,
    int n, int e, int nbc, int neb) {
    __shared__ char sbuf[16384 + 8192 + (NBC_MAX * 3 + 1) * 4];  // 30.7 KB

    if ((int)blockIdx.x >= neb) {
        // ---------------- gemm path ----------------
        unsigned short* Wh = (unsigned short*)sbuf;  // [col][136]
        {
            const float4* wg4 = (const float4*)Wg;  // [k=128][col=64]
#pragma unroll
            for (int i = 0; i < 8; ++i) {
                int f = threadIdx.x + i * 256;
                float4 w = wg4[f];
                int k = f >> 4;
                int c0 = (f & 15) << 2;
                Wh[(c0 + 0) * 136 + k] = f2bf(w.x);
                Wh[(c0 + 1) * 136 + k] = f2bf(w.y);
                Wh[(c0 + 2) * 136 + k] = f2bf(w.z);
                Wh[(c0 + 3) * 136 + k] = f2bf(w.w);
            }
        }
        __syncthreads();

        const int lane = threadIdx.x & 63;
        const int wave = threadIdx.x >> 6;
        const int rb = ((int)blockIdx.x - neb) * 64 + wave * 16;
        const int arow = rb + (lane & 15);
        const int kb = (lane >> 4) << 3;
        const int col = lane & 15;

        f32x4 acc[4];
#pragma unroll
        for (int ct = 0; ct < 4; ++ct) acc[ct] = (f32x4){0.f, 0.f, 0.f, 0.f};

#pragma unroll
        for (int ks = 0; ks < 4; ++ks) {
            const int k0 = ks * 32 + kb;
            float av[8];
            if (arow < n) {
                float4 a0 = *(const float4*)(x + (size_t)arow * 128 + k0);
                float4 a1 = *(const float4*)(x + (size_t)arow * 128 + k0 + 4);
                av[0] = a0.x; av[1] = a0.y; av[2] = a0.z; av[3] = a0.w;
                av[4] = a1.x; av[5] = a1.y; av[6] = a1.z; av[7] = a1.w;
            } else {
#pragma unroll
                for (int j = 0; j < 8; ++j) av[j] = 0.f;
            }
            bf16x8 ah;
#pragma unroll
            for (int j = 0; j < 8; ++j) ah[j] = (short)f2bf(av[j]);
#pragma unroll
            for (int ct = 0; ct < 4; ++ct) {
                const bf16x8 bh = *(const bf16x8*)(&Wh[(ct * 16 + col) * 136 + k0]);
                acc[ct] = __builtin_amdgcn_mfma_f32_16x16x32_bf16(ah, bh, acc[ct], 0, 0, 0);
            }
        }

        float as_f[4], ad_f[4];
#pragma unroll
        for (int ct = 0; ct < 4; ++ct) {
            as_f[ct] = att_s[ct * 16 + col];
            ad_f[ct] = att_d[ct * 16 + col];
        }
#pragma unroll
        for (int reg = 0; reg < 4; ++reg) {
            const int row = rb + ((lane >> 4) << 2) + reg;
            float s = 0.f, t = 0.f;
#pragma unroll
            for (int ct = 0; ct < 4; ++ct) {
                float v = acc[ct][reg];
                s = fmaf(v, as_f[ct], s);
                t = fmaf(v, ad_f[ct], t);
                if (row < n) h2[(size_t)row * 64 + ct * 16 + col] = f2bf(v);
            }
#pragma unroll
            for (int o = 1; o < 16; o <<= 1) {
                s += __shfl_xor(s, o);
                t += __shfl_xor(t, o);
            }
            if (col == 0 && row < n) { a_src[row] = s; a_dst[row] = t; }
        }
    } else {
        // ---------------- cscatter path ----------------
        int* wordA = (int*)sbuf;                            // [4096]
        unsigned short* buckA = (unsigned short*)(sbuf + 16384);  // [4096]
        int* meta  = (int*)(sbuf + 24576);
        int* sc    = meta;                 // [NBC_MAX+1]
        int* offs  = meta + NBC_MAX + 1;   // [NBC_MAX]
        int* gbase = meta + 2 * NBC_MAX + 1;
        const int tid = threadIdx.x;
        for (int t = tid; t < nbc; t += 256) { sc[t] = 0; offs[t] = 0; }
        __syncthreads();
        const int base = (int)blockIdx.x * 4096;
        int s_[16], d_[16];
#pragma unroll
        for (int k = 0; k < 4; ++k) {
            const int i0 = base + (k * 256 + tid) * 4;
            if (i0 + 4 <= e) {
                int4 s4 = *(const int4*)(srcv + i0);
                int4 d4 = *(const int4*)(dstv + i0);
                s_[k * 4 + 0] = s4.x; d_[k * 4 + 0] = d4.x;
                s_[k * 4 + 1] = s4.y; d_[k * 4 + 1] = d4.y;
                s_[k * 4 + 2] = s4.z; d_[k * 4 + 2] = d4.z;
                s_[k * 4 + 3] = s4.w; d_[k * 4 + 3] = d4.w;
            } else {
#pragma unroll
                for (int j = 0; j < 4; ++j) {
                    int i = i0 + j;
                    if (i < e) { s_[k * 4 + j] = srcv[i]; d_[k * 4 + j] = dstv[i]; }
                    else d_[k * 4 + j] = -1;
                }
            }
        }
#pragma unroll
        for (int k = 0; k < 16; ++k)
            if (d_[k] >= 0) atomicAdd(&sc[d_[k] >> 8], 1);
        lds_excl_scan(sc, nbc);
        for (int t = tid; t < nbc; t += 256) {
            int c = sc[t + 1] - sc[t];
            if (c) gbase[t] = t * SCAP + atomicAdd(&gcursor[t], c);
        }
        __syncthreads();
#pragma unroll
        for (int k = 0; k < 16; ++k) {
            if (d_[k] >= 0) {
                int bb = d_[k] >> 8;
                int r = atomicAdd(&offs[bb], 1);
                int idx = sc[bb] + r;
                wordA[idx] = ((d_[k] & 255) << 17) | s_[k];
                buckA[idx] = (unsigned short)bb;
            }
        }
        __syncthreads();
        const int tot = sc[nbc];
        for (int p = tid; p < tot; p += 256) {
            int bb = buckA[p];
            int gi = gbase[bb] + (p - sc[bb]);
            if (gi < (bb + 1) * SCAP) {  // overflow clamp (never hot)
                words[gi] = wordA[p];
            }
        }
    }
}

// ------------------------------------------------- fine sort (pure, 1-read)
__global__ __launch_bounds__(256) void k_fsort(
    const int* __restrict__ words, const int* __restrict__ gcursor,
    int* __restrict__ words2, int* __restrict__ rowptrB, int n) {
    __shared__ int rp[257];
    __shared__ int offs[256];
    __shared__ int staged[SCAP];    // 24 KB
    __shared__ int sorted_[SCAP];   // 24 KB
    const int b = blockIdx.x;
    const int base = b * SCAP;
    const int cnt = min(gcursor[b], SCAP);
    const int tid = threadIdx.x;
    rp[tid] = 0;
    offs[tid] = 0;
    if (tid == 0) rp[256] = 0;
    __syncthreads();
    for (int p = tid; p < cnt; p += 256) {
        int w = words[base + p];
        staged[p] = w;
        atomicAdd(&rp[(w >> 17) & 255], 1);
    }
    lds_excl_scan(rp, 256);
    for (int p = tid; p < cnt; p += 256) {
        int w = staged[p];
        int dl = (w >> 17) & 255;
        int r = atomicAdd(&offs[dl], 1);
        sorted_[rp[dl] + r] = w;
    }
    __syncthreads();
    const int cnt4 = cnt >> 2;
    for (int q = tid; q < cnt4; q += 256)
        ((int4*)(words2 + base))[q] = ((const int4*)sorted_)[q];
    for (int p = (cnt4 << 2) + tid; p < cnt; p += 256)
        words2[base + p] = sorted_[p];
    for (int t = tid; t <= 256; t += 256)
        rowptrB[b * 257 + t] = base + rp[t];
}

// ------------------------------------------------- weighted gather-aggregate
// 4 dsts/wave (16 lanes/dst: 2 row-pairs x 8 feat-octets); 32-edge chunks
// (2 guarded words2 loads + inline alpha per lane). Single uniform loop.
__global__ __launch_bounds__(256) void k_aggr(
    const unsigned short* __restrict__ h2, const float* __restrict__ a_src,
    const float* __restrict__ a_dst, const int* __restrict__ rowptrB,
    const int* __restrict__ words2, float* __restrict__ out, int n) {
    const int lane = threadIdx.x & 63;
    const int wave = threadIdx.x >> 6;
    const int d = blockIdx.x * 16 + wave * 4 + (lane >> 4);
    if (d >= n) return;
    const int b = d >> 8;
    const int dl = d & 255;
    const int s0 = rowptrB[b * 257 + dl];
    const int deg = rowptrB[b * 257 + dl + 1] - s0;
    const float adstd = a_dst[d];
    const float wself = __expf(leaky(a_src[d] + adstd));

    const int r = (lane >> 3) & 1;    // row pair 0/1
    const int f0 = (lane & 7) << 3;   // feature octet
    const int gb = lane & 48;         // group base lane
    const int lane15 = lane & 15;
    float acc[8] = {0.f, 0.f, 0.f, 0.f, 0.f, 0.f, 0.f, 0.f};
    float wsum_l = 0.f;
    if (r == 0) {  // self loop
        int4 u = *(const int4*)(h2 + (size_t)d * 64 + f0);
        bf8_fma(acc, u, wself);
    }
    for (int cb = 0; cb < deg; cb += 32) {
        const int jA = cb + lane15;
        const int jB = jA + 16;
        int srcA = 0, srcB = 0;
        float wA = 0.f, wB = 0.f;
        if (jA < deg) srcA = words2[s0 + jA] & 0x1FFFF;
        if (jB < deg) srcB = words2[s0 + jB] & 0x1FFFF;
        if (jA < deg) wA = __expf(leaky(a_src[srcA] + adstd));
        if (jB < deg) wB = __expf(leaky(a_src[srcB] + adstd));
        wsum_l += wA + wB;
        const int cnt = min(32, deg - cb);
#pragma unroll
        for (int c0 = 0; c0 < 16; c0 += 2) {
            const int sl = gb | (c0 + r);
            int sjA = __shfl(srcA, sl);
            float wjA = __shfl(wA, sl);
            int sjB = __shfl(srcB, sl);
            float wjB = __shfl(wB, sl);
            if (c0 + r < cnt) {
                int4 u = *(const int4*)(h2 + (size_t)sjA * 64 + f0);
                bf8_fma(acc, u, wjA);
            }
            if (16 + c0 + r < cnt) {
                int4 u = *(const int4*)(h2 + (size_t)sjB * 64 + f0);
                bf8_fma(acc, u, wjB);
            }
        }
    }
    // wsum over the 16-lane group
#pragma unroll
    for (int o = 8; o >= 1; o >>= 1) wsum_l += __shfl_xor(wsum_l, o);
    const float inv = 1.0f / (wsum_l + wself + 1e-16f);
    // combine row pairs
#pragma unroll
    for (int i = 0; i < 8; ++i) acc[i] += __shfl_xor(acc[i], 8);
    if (r == 0) {
        float* op = out + (size_t)d * 64 + f0;
        *(float4*)op = make_float4(acc[0] * inv, acc[1] * inv,
                                   acc[2] * inv, acc[3] * inv);
        *(float4*)(op + 4) = make_float4(acc[4] * inv, acc[5] * inv,
                                         acc[6] * inv, acc[7] * inv);
    }
}

extern "C" void kernel_launch(void* const* d_in, const int* in_sizes, int n_in,
                              void* d_out, int out_size, void* d_ws, size_t ws_size,
                              hipStream_t stream) {
    const float* x = (const float*)d_in[0];
    const float* W = (const float*)d_in[1];
    const float* att_s = (const float*)d_in[2];
    const float* att_d = (const float*)d_in[3];
    const int* ei = (const int*)d_in[4];
    const int n = in_sizes[0] / 128;
    const int e = in_sizes[4] / 2;
    const int* srcv = ei;
    const int* dstv = ei + e;
    float* out = (float*)d_out;

    char* ws = (char*)d_ws;
    size_t off = 0;
    auto carve = [&](size_t bytes) -> void* {
        void* p = ws + off;
        off = (off + bytes + 63) & ~(size_t)63;
        return p;
    };
    const int nbc = (n + 255) >> 8;  // coarse buckets (<= NBC_MAX)
    unsigned short* h2 = (unsigned short*)carve((size_t)n * 64 * 2);
    float* a_src  = (float*)carve((size_t)n * 4);
    float* a_dst  = (float*)carve((size_t)n * 4);
    int* gcursor  = (int*)carve((size_t)NBC_MAX * 4);
    int* rowptrB  = (int*)carve((size_t)nbc * 257 * 4);
    int* words    = (int*)carve((size_t)nbc * SCAP * 4);
    int* words2   = (int*)carve((size_t)nbc * SCAP * 4);
    (void)ws_size; (void)n_in; (void)out_size;

    const int neb = (e + 4095) / 4096;
    const int gB = (n + 63) / 64;

    hipMemsetAsync(gcursor, 0, (size_t)NBC_MAX * 4, stream);
    k_fused<<<neb + gB, 256, 0, stream>>>(x, W, att_s, att_d, h2, a_src, a_dst,
                                          srcv, dstv, gcursor, words, n, e, nbc, neb);
    k_fsort<<<nbc, 256, 0, stream>>>(words, gcursor, words2, rowptrB, n);
    k_aggr<<<(n + 15) / 16, 256, 0, stream>>>(h2, a_src, a_dst, rowptrB, words2, out, n);
}